// Round 1
// baseline (68048.474 us; speedup 1.0000x reference)
//
#include <hip/hip_runtime.h>
#include <hip/hip_cooperative_groups.h>
#include <hip/hip_bf16.h>

namespace cg = cooperative_groups;

#define B_  64
#define T_  128
#define E_  512
#define HH_ 256
#define HN_ 1024
#define D_  4
#define V_  10000
#define NR_ (T_*D_)   // 512 chained updates

// -------------------------------------------------------------------------
// Persistent cooperative recurrence kernel.
// Grid: 256 WGs x 256 threads. One grid.sync per round, 513 rounds.
// Round r: sH-chain performs update r (t=r/4, i=r%4) reading sH[p].
//          sN-chain performs update s=r-1 reading sN[p] and sH[p]
//          (sH[p] at round r is the state AFTER sH-update r-1, which is
//           exactly the sH the reference uses for z at step s).
// Thread mapping (sN side): b = tau>>2, jj = tau&3, j = w*4 + jj.
//   -> Wh rows j, j+HN read wave-broadcast (16 lanes/addr), each row read
//      exactly once per round across the grid.
// sH side: wave 3 of each WG handles one (b,c) item: 2 Whh-row dots + gate.
// -------------------------------------------------------------------------
__global__ __launch_bounds__(256) void recur_kernel(
    const int*   __restrict__ xx,
    const float* __restrict__ embed,
    const float* __restrict__ Whh, const float* __restrict__ bhh,
    const float* __restrict__ Wih, const float* __restrict__ bih,
    const float* __restrict__ Wh,  const float* __restrict__ bh,
    const float* __restrict__ Wi,  const float* __restrict__ bi,
    const float* __restrict__ Wup, const float* __restrict__ bup,
    float* __restrict__ sH,   // [2][B_][HH_]
    float* __restrict__ sN,   // [2][B_][HN_]
    float* __restrict__ hOut) // [B_*T_][HN_]
{
    cg::grid_group grid = cg::this_grid();
    const int w   = blockIdx.x;
    const int tau = threadIdx.x;
    const int gid = w * 256 + tau;

    // zero-init sH[parity 0] and sN[parity 1] (ws is poisoned 0xAA)
    if (gid < B_ * HH_) sH[gid] = 0.f;
    sN[B_ * HN_ + gid] = 0.f;
    grid.sync();

    // sN-side mapping
    const int b  = tau >> 2;
    const int jj = tau & 3;
    const int j  = w * 4 + jj;

    // sH-side mapping (wave 3 only)
    const int lane = tau - 192;
    const int item = w * 64 + lane;     // valid when tau>=192: 0..16383
    const int bh_i = item >> 8;         // batch row
    const int ch   = item & 255;        // sH column

    for (int r = 0; r <= NR_; ++r) {
        const int p = r & 1;
        const float* sNp = sN + p * (B_ * HN_);
        const float* sHp = sH + p * (B_ * HH_);
        float* sNn = sN + (1 - p) * (B_ * HN_);
        float* sHn = sH + (1 - p) * (B_ * HH_);

        // ---------------- sN chain: update s = r-1 ----------------
        if (r >= 1) {
            const int s = r - 1;
            const int t = s >> 2;
            const int i = s & 3;

            float acc1 = bh[j];
            float acc2 = bh[j + HN_];
            const float4* sv = (const float4*)(sNp + b * HN_);
            const float4* w1 = (const float4*)(Wh + (size_t)j * HN_);
            const float4* w2 = (const float4*)(Wh + (size_t)(j + HN_) * HN_);
            #pragma unroll 8
            for (int k = 0; k < HN_ / 4; ++k) {
                float4 a = sv[k], x1 = w1[k], x2 = w2[k];
                acc1 += a.x * x1.x + a.y * x1.y + a.z * x1.z + a.w * x1.w;
                acc2 += a.x * x2.x + a.y * x2.y + a.z * x2.z + a.w * x2.w;
            }
            if (i == 0) {  // + (xt @ Wi.T + bi), computed on the fly
                const int tok = xx[b * T_ + t];
                const float4* ev = (const float4*)(embed + (size_t)tok * E_);
                const float4* y1 = (const float4*)(Wi + (size_t)j * E_);
                const float4* y2 = (const float4*)(Wi + (size_t)(j + HN_) * E_);
                float e1 = bi[j], e2 = bi[j + HN_];
                #pragma unroll 8
                for (int k = 0; k < E_ / 4; ++k) {
                    float4 a = ev[k], x1 = y1[k], x2 = y2[k];
                    e1 += a.x * x1.x + a.y * x1.y + a.z * x1.z + a.w * x1.w;
                    e2 += a.x * x2.x + a.y * x2.y + a.z * x2.z + a.w * x2.w;
                }
                acc1 += e1; acc2 += e2;
            }
            // z = sH_new @ Wup.T + bup  (sHp IS the post-update-(s) sH)
            float zv = bup[j];
            {
                const float4* hv = (const float4*)(sHp + b * HH_);
                const float4* wu = (const float4*)(Wup + (size_t)j * HH_);
                #pragma unroll 8
                for (int k = 0; k < HH_ / 4; ++k) {
                    float4 a = hv[k], x1 = wu[k];
                    zv += a.x * x1.x + a.y * x1.y + a.z * x1.z + a.w * x1.w;
                }
            }
            const float g_h = acc1 * zv;
            const float g_t = acc2 * zv;
            const float sg  = 1.f / (1.f + expf(-g_t));
            const float ov  = sNp[b * HN_ + j];
            const float nv  = tanhf(g_h) * sg + ov * (1.f - sg);
            sNn[b * HN_ + j] = nv;
            if (i == D_ - 1) hOut[(size_t)(b * T_ + t) * HN_ + j] = nv;
        }

        // ---------------- sH chain: update r ----------------
        if (r < NR_ && tau >= 192) {
            const int t = r >> 2;
            const int i = r & 3;
            float a1 = bhh[ch];
            float a2 = bhh[ch + HH_];
            const float4* svh = (const float4*)(sHp + bh_i * HH_);
            const float4* q1  = (const float4*)(Whh + (size_t)ch * HH_);
            const float4* q2  = (const float4*)(Whh + (size_t)(ch + HH_) * HH_);
            #pragma unroll 8
            for (int k = 0; k < HH_ / 4; ++k) {
                float4 a = svh[k], x1 = q1[k], x2 = q2[k];
                a1 += a.x * x1.x + a.y * x1.y + a.z * x1.z + a.w * x1.w;
                a2 += a.x * x2.x + a.y * x2.y + a.z * x2.z + a.w * x2.w;
            }
            if (i == 0) {  // + (xt @ Wih.T + bih)
                const int tok = xx[bh_i * T_ + t];
                const float4* ev = (const float4*)(embed + (size_t)tok * E_);
                const float4* y1 = (const float4*)(Wih + (size_t)ch * E_);
                const float4* y2 = (const float4*)(Wih + (size_t)(ch + HH_) * E_);
                #pragma unroll 8
                for (int k = 0; k < E_ / 4; ++k) {
                    float4 a = ev[k], x1 = y1[k], x2 = y2[k];
                    a1 += a.x * x1.x + a.y * x1.y + a.z * x1.z + a.w * x1.w;
                    a2 += a.x * x2.x + a.y * x2.y + a.z * x2.z + a.w * x2.w;
                }
                a1 += bih[ch]; a2 += bih[ch + HH_];
            }
            const float sg = 1.f / (1.f + expf(-a2));
            const float ov = sHp[bh_i * HH_ + ch];
            sHn[bh_i * HH_ + ch] = tanhf(a1) * sg + ov * (1.f - sg);
        }

        grid.sync();
    }
}

// -------------------------------------------------------------------------
// Output projection: out[bt, v] = h[bt, :] . Wout[v, :] + bout[v]
// M=8192, N=10000, K=1024. 64x64 tile, 256 threads, 4x4 acc/thread.
// -------------------------------------------------------------------------
__global__ __launch_bounds__(256) void out_gemm(
    const float* __restrict__ hb, const float* __restrict__ Wout,
    const float* __restrict__ bout, float* __restrict__ op)
{
    __shared__ float Ht[32][64];  // [k][m]
    __shared__ float Wt[32][64];  // [k][n]
    const int tau = threadIdx.x;
    const int tx  = tau & 15;
    const int ty  = tau >> 4;
    const int m0  = blockIdx.x * 64;
    const int n0  = blockIdx.y * 64;
    float acc[4][4] = {{0.f}};

    for (int k0 = 0; k0 < HN_; k0 += 32) {
        #pragma unroll
        for (int l = 0; l < 2; ++l) {
            const int f   = tau + l * 256;   // 0..511
            const int row = f >> 3;          // 64 rows
            const int kq  = (f & 7) * 4;     // 8 float4 per row
            float4 hv = *(const float4*)(hb + (size_t)(m0 + row) * HN_ + k0 + kq);
            Ht[kq + 0][row] = hv.x; Ht[kq + 1][row] = hv.y;
            Ht[kq + 2][row] = hv.z; Ht[kq + 3][row] = hv.w;
            const int vr = n0 + row;
            float4 wv = (vr < V_) ? *(const float4*)(Wout + (size_t)vr * HN_ + k0 + kq)
                                  : make_float4(0.f, 0.f, 0.f, 0.f);
            Wt[kq + 0][row] = wv.x; Wt[kq + 1][row] = wv.y;
            Wt[kq + 2][row] = wv.z; Wt[kq + 3][row] = wv.w;
        }
        __syncthreads();
        #pragma unroll
        for (int kk = 0; kk < 32; ++kk) {
            float4 av = *(const float4*)(&Ht[kk][ty * 4]);
            float4 bv = *(const float4*)(&Wt[kk][tx * 4]);
            acc[0][0] += av.x * bv.x; acc[0][1] += av.x * bv.y;
            acc[0][2] += av.x * bv.z; acc[0][3] += av.x * bv.w;
            acc[1][0] += av.y * bv.x; acc[1][1] += av.y * bv.y;
            acc[1][2] += av.y * bv.z; acc[1][3] += av.y * bv.w;
            acc[2][0] += av.z * bv.x; acc[2][1] += av.z * bv.y;
            acc[2][2] += av.z * bv.z; acc[2][3] += av.z * bv.w;
            acc[3][0] += av.w * bv.x; acc[3][1] += av.w * bv.y;
            acc[3][2] += av.w * bv.z; acc[3][3] += av.w * bv.w;
        }
        __syncthreads();
    }

    #pragma unroll
    for (int ii = 0; ii < 4; ++ii) {
        const int m = m0 + ty * 4 + ii;
        #pragma unroll
        for (int jq = 0; jq < 4; ++jq) {
            const int v = n0 + tx * 4 + jq;
            if (v < V_) op[(size_t)m * V_ + v] = acc[ii][jq] + bout[v];
        }
    }
}

extern "C" void kernel_launch(void* const* d_in, const int* in_sizes, int n_in,
                              void* d_out, int out_size, void* d_ws, size_t ws_size,
                              hipStream_t stream) {
    const int*   xx    = (const int*)  d_in[0];
    const float* embed = (const float*)d_in[1];
    const float* Whh   = (const float*)d_in[2];
    const float* bhh   = (const float*)d_in[3];
    const float* Wih   = (const float*)d_in[4];
    const float* bih   = (const float*)d_in[5];
    const float* Wh    = (const float*)d_in[6];
    const float* bh    = (const float*)d_in[7];
    const float* Wi    = (const float*)d_in[8];
    const float* bi    = (const float*)d_in[9];
    const float* Wup   = (const float*)d_in[10];
    const float* bup   = (const float*)d_in[11];
    const float* Wout  = (const float*)d_in[12];
    const float* bout  = (const float*)d_in[13];

    float* ws   = (float*)d_ws;
    float* hbuf = ws;                                   // 8192*1024 floats
    float* sHb  = hbuf + (size_t)B_ * T_ * HN_;         // 2*64*256
    float* sNb  = sHb + 2 * B_ * HH_;                   // 2*64*1024

    void* args[] = { (void*)&xx, (void*)&embed, (void*)&Whh, (void*)&bhh,
                     (void*)&Wih, (void*)&bih, (void*)&Wh, (void*)&bh,
                     (void*)&Wi, (void*)&bi, (void*)&Wup, (void*)&bup,
                     (void*)&sHb, (void*)&sNb, (void*)&hbuf };
    hipLaunchCooperativeKernel(reinterpret_cast<void*>(recur_kernel),
                               dim3(256), dim3(256), args, 0, stream);

    out_gemm<<<dim3(T_ * B_ / 64, (V_ + 63) / 64), 256, 0, stream>>>(
        hbuf, Wout, bout, (float*)d_out);
}

// Round 2
// 30711.920 us; speedup vs baseline: 2.2157x; 2.2157x over previous
//
#include <hip/hip_runtime.h>
#include <hip/hip_cooperative_groups.h>

namespace cg = cooperative_groups;

#define B_  64
#define T_  128
#define E_  512
#define HH_ 256
#define HN_ 1024
#define D_  4
#define V_  10000
#define NR_ (T_*D_)   // 512 chained updates

// ---- dynamic LDS layout (float offsets). Rows padded +4 floats so the 4
// jj-rows hit disjoint banks (pad 1024->1028 etc.; 2-way aliasing is free). ----
#define WH_OFF   0            // Wh:  8 rows x 1028   (rows w*4+jj, +HN)
#define WU_OFF   8224         // Wup: 4 rows x 260    (rows w*4+jj)
#define WI_OFF   9264         // Wi:  8 rows x 516    (rows w*4+jj, +HN)
#define WHH_OFF  13392        // Whh: 32 rows x 260   (rows ch0+rr, +HH)
#define WIH_OFF  21712        // Wih: 32 rows x 516
#define LDS_FLOATS 38224      // 152896 B  -> 1 WG/CU (intentional)

// -------------------------------------------------------------------------
// Persistent cooperative recurrence. 256 WGs x 256 thr, 513 rounds.
// All per-WG weights live in LDS (persist across grid.sync -> immune to the
// per-round L1/L2 coherence flush). Per-round global loads = state only,
// explicitly pipelined 16 float4s deep for MLP at 1 wave/SIMD.
// -------------------------------------------------------------------------
__global__ __launch_bounds__(256, 1) void recur_kernel(
    const int*   __restrict__ xx,
    const float* __restrict__ embed,
    const float* __restrict__ Whh, const float* __restrict__ bhh,
    const float* __restrict__ Wih, const float* __restrict__ bih,
    const float* __restrict__ Wh,  const float* __restrict__ bh,
    const float* __restrict__ Wi,  const float* __restrict__ bi,
    const float* __restrict__ Wup, const float* __restrict__ bup,
    float* __restrict__ sH,   // [2][B_][HH_]
    float* __restrict__ sN,   // [2][B_][HN_]
    float* __restrict__ hOut) // [B_*T_][HN_]
{
    extern __shared__ float lds[];
    cg::grid_group grid = cg::this_grid();
    const int w   = blockIdx.x;
    const int tau = threadIdx.x;
    const int gid = w * 256 + tau;
    const int ch0 = (w & 15) * 16;

    // ---------------- stage per-WG weights into LDS (once) ----------------
    for (int idx = tau; idx < 2048; idx += 256) {          // Wh 8x1024
        int r = idx >> 8, kq = idx & 255;
        int grow = w*4 + (r & 3) + (r >> 2) * HN_;
        *(float4*)&lds[WH_OFF + r*1028 + kq*4] =
            *(const float4*)(Wh + (size_t)grow * HN_ + kq*4);
    }
    for (int idx = tau; idx < 256; idx += 256) {           // Wup 4x256
        int r = idx >> 6, kq = idx & 63;
        *(float4*)&lds[WU_OFF + r*260 + kq*4] =
            *(const float4*)(Wup + (size_t)(w*4 + r) * HH_ + kq*4);
    }
    for (int idx = tau; idx < 1024; idx += 256) {          // Wi 8x512
        int r = idx >> 7, kq = idx & 127;
        int grow = w*4 + (r & 3) + (r >> 2) * HN_;
        *(float4*)&lds[WI_OFF + r*516 + kq*4] =
            *(const float4*)(Wi + (size_t)grow * E_ + kq*4);
    }
    for (int idx = tau; idx < 2048; idx += 256) {          // Whh 32x256
        int r = idx >> 6, kq = idx & 63;
        int grow = ch0 + (r & 15) + (r >> 4) * HH_;
        *(float4*)&lds[WHH_OFF + r*260 + kq*4] =
            *(const float4*)(Whh + (size_t)grow * HH_ + kq*4);
    }
    for (int idx = tau; idx < 4096; idx += 256) {          // Wih 32x512
        int r = idx >> 7, kq = idx & 127;
        int grow = ch0 + (r & 15) + (r >> 4) * HH_;
        *(float4*)&lds[WIH_OFF + r*516 + kq*4] =
            *(const float4*)(Wih + (size_t)grow * E_ + kq*4);
    }

    // init states (ws is poisoned 0xAA): sH parity 0, sN parity 1
    if (gid < B_ * HH_) sH[gid] = 0.f;
    sN[B_ * HN_ + gid] = 0.f;
    __syncthreads();
    grid.sync();

    // ---------------- per-thread constants ----------------
    // sN side: thread = (b, jj), output column j = w*4+jj (and j+HN_)
    const int b  = tau >> 2;
    const int jj = tau & 3;
    const int j  = w * 4 + jj;
    const float bh1 = bh[j],  bh2 = bh[j + HN_];
    const float bi1 = bi[j],  bi2 = bi[j + HN_];
    const float bupj = bup[j];
    const float* wr1 = lds + WH_OFF + jj * 1028;
    const float* wr2 = lds + WH_OFF + (4 + jj) * 1028;
    const float* yr1 = lds + WI_OFF + jj * 516;
    const float* yr2 = lds + WI_OFF + (4 + jj) * 516;
    const float* ur  = lds + WU_OFF + jj * 260;

    // sH side: lanes tau%4==3 (spread across all 4 waves). item=(bH, ch)
    const bool hduty = (tau & 3) == 3;
    const int lane = tau >> 2;                  // 0..63
    const int ch   = ch0 + (lane & 15);
    const int bH   = (w >> 4) * 4 + (lane >> 4);
    const float bhh1 = bhh[ch], bhh2 = bhh[ch + HH_];
    const float bih1 = bih[ch], bih2 = bih[ch + HH_];
    const float* q1 = lds + WHH_OFF + (ch & 15) * 260;
    const float* q2 = lds + WHH_OFF + (16 + (ch & 15)) * 260;
    const float* p1 = lds + WIH_OFF + (ch & 15) * 516;
    const float* p2 = lds + WIH_OFF + (16 + (ch & 15)) * 516;

    for (int r = 0; r <= NR_; ++r) {
        const int p = r & 1;
        const float* sNp = sN + p * (B_ * HN_);
        const float* sHp = sH + p * (B_ * HH_);
        float* sNn = sN + (1 - p) * (B_ * HN_);
        float* sHn = sH + (1 - p) * (B_ * HH_);

        // ---------------- sN chain: update s = r-1 ----------------
        if (r >= 1) {
            const int s = r - 1;
            const int t = s >> 2;
            const int i = s & 3;

            float acc1 = bh1, acc2 = bh2;
            const float4* sv = (const float4*)(sNp + b * HN_);
            for (int kc = 0; kc < 256; kc += 16) {
                float4 sreg[16];
                #pragma unroll
                for (int u = 0; u < 16; ++u) sreg[u] = sv[kc + u];
                #pragma unroll
                for (int u = 0; u < 16; ++u) {
                    float4 a  = sreg[u];
                    float4 x1 = *(const float4*)(wr1 + (kc + u) * 4);
                    float4 x2 = *(const float4*)(wr2 + (kc + u) * 4);
                    acc1 += a.x*x1.x + a.y*x1.y + a.z*x1.z + a.w*x1.w;
                    acc2 += a.x*x2.x + a.y*x2.y + a.z*x2.z + a.w*x2.w;
                }
            }
            if (i == 0) {   // + (xt @ Wi.T + bi)
                const int tok = xx[b * T_ + t];
                const float4* ev = (const float4*)(embed + (size_t)tok * E_);
                float e1 = bi1, e2 = bi2;
                for (int kc = 0; kc < 128; kc += 16) {
                    float4 sreg[16];
                    #pragma unroll
                    for (int u = 0; u < 16; ++u) sreg[u] = ev[kc + u];
                    #pragma unroll
                    for (int u = 0; u < 16; ++u) {
                        float4 a  = sreg[u];
                        float4 x1 = *(const float4*)(yr1 + (kc + u) * 4);
                        float4 x2 = *(const float4*)(yr2 + (kc + u) * 4);
                        e1 += a.x*x1.x + a.y*x1.y + a.z*x1.z + a.w*x1.w;
                        e2 += a.x*x2.x + a.y*x2.y + a.z*x2.z + a.w*x2.w;
                    }
                }
                acc1 += e1; acc2 += e2;
            }
            // z = sH_new @ Wup.T + bup  (sHp IS post-update-(s) sH)
            float zv = bupj;
            {
                const float4* hv = (const float4*)(sHp + b * HH_);
                for (int kc = 0; kc < 64; kc += 16) {
                    float4 sreg[16];
                    #pragma unroll
                    for (int u = 0; u < 16; ++u) sreg[u] = hv[kc + u];
                    #pragma unroll
                    for (int u = 0; u < 16; ++u) {
                        float4 a  = sreg[u];
                        float4 x1 = *(const float4*)(ur + (kc + u) * 4);
                        zv += a.x*x1.x + a.y*x1.y + a.z*x1.z + a.w*x1.w;
                    }
                }
            }
            const float g_h = acc1 * zv;
            const float g_t = acc2 * zv;
            const float sg  = 1.f / (1.f + expf(-g_t));
            const float ov  = sNp[b * HN_ + j];
            const float nv  = tanhf(g_h) * sg + ov * (1.f - sg);
            sNn[b * HN_ + j] = nv;
            if (i == D_ - 1) hOut[(size_t)(b * T_ + t) * HN_ + j] = nv;
        }

        // ---------------- sH chain: update r ----------------
        if (r < NR_ && hduty) {
            const int t = r >> 2;
            const int i = r & 3;
            float a1 = bhh1, a2 = bhh2;
            const float4* svh = (const float4*)(sHp + bH * HH_);
            for (int kc = 0; kc < 64; kc += 16) {
                float4 sreg[16];
                #pragma unroll
                for (int u = 0; u < 16; ++u) sreg[u] = svh[kc + u];
                #pragma unroll
                for (int u = 0; u < 16; ++u) {
                    float4 a  = sreg[u];
                    float4 x1 = *(const float4*)(q1 + (kc + u) * 4);
                    float4 x2 = *(const float4*)(q2 + (kc + u) * 4);
                    a1 += a.x*x1.x + a.y*x1.y + a.z*x1.z + a.w*x1.w;
                    a2 += a.x*x2.x + a.y*x2.y + a.z*x2.z + a.w*x2.w;
                }
            }
            if (i == 0) {   // + (xt @ Wih.T + bih)
                const int tok = xx[bH * T_ + t];
                const float4* ev = (const float4*)(embed + (size_t)tok * E_);
                for (int kc = 0; kc < 128; kc += 16) {
                    float4 sreg[16];
                    #pragma unroll
                    for (int u = 0; u < 16; ++u) sreg[u] = ev[kc + u];
                    #pragma unroll
                    for (int u = 0; u < 16; ++u) {
                        float4 a  = sreg[u];
                        float4 x1 = *(const float4*)(p1 + (kc + u) * 4);
                        float4 x2 = *(const float4*)(p2 + (kc + u) * 4);
                        a1 += a.x*x1.x + a.y*x1.y + a.z*x1.z + a.w*x1.w;
                        a2 += a.x*x2.x + a.y*x2.y + a.z*x2.z + a.w*x2.w;
                    }
                }
                a1 += bih1; a2 += bih2;
            }
            const float sg = 1.f / (1.f + expf(-a2));
            const float ov = sHp[bH * HH_ + ch];
            sHn[bH * HH_ + ch] = tanhf(a1) * sg + ov * (1.f - sg);
        }

        grid.sync();
    }
}

// -------------------------------------------------------------------------
// Output projection: out[bt, v] = h[bt, :] . Wout[v, :] + bout[v]
// M=8192, N=10000, K=1024. 64x64 tile, 256 threads, 4x4 acc/thread.
// -------------------------------------------------------------------------
__global__ __launch_bounds__(256) void out_gemm(
    const float* __restrict__ hb, const float* __restrict__ Wout,
    const float* __restrict__ bout, float* __restrict__ op)
{
    __shared__ float Ht[32][64];  // [k][m]
    __shared__ float Wt[32][64];  // [k][n]
    const int tau = threadIdx.x;
    const int tx  = tau & 15;
    const int ty  = tau >> 4;
    const int m0  = blockIdx.x * 64;
    const int n0  = blockIdx.y * 64;
    float acc[4][4] = {{0.f}};

    for (int k0 = 0; k0 < HN_; k0 += 32) {
        #pragma unroll
        for (int l = 0; l < 2; ++l) {
            const int f   = tau + l * 256;   // 0..511
            const int row = f >> 3;          // 64 rows
            const int kq  = (f & 7) * 4;     // 8 float4 per row
            float4 hv = *(const float4*)(hb + (size_t)(m0 + row) * HN_ + k0 + kq);
            Ht[kq + 0][row] = hv.x; Ht[kq + 1][row] = hv.y;
            Ht[kq + 2][row] = hv.z; Ht[kq + 3][row] = hv.w;
            const int vr = n0 + row;
            float4 wv = (vr < V_) ? *(const float4*)(Wout + (size_t)vr * HN_ + k0 + kq)
                                  : make_float4(0.f, 0.f, 0.f, 0.f);
            Wt[kq + 0][row] = wv.x; Wt[kq + 1][row] = wv.y;
            Wt[kq + 2][row] = wv.z; Wt[kq + 3][row] = wv.w;
        }
        __syncthreads();
        #pragma unroll
        for (int kk = 0; kk < 32; ++kk) {
            float4 av = *(const float4*)(&Ht[kk][ty * 4]);
            float4 bv = *(const float4*)(&Wt[kk][tx * 4]);
            acc[0][0] += av.x * bv.x; acc[0][1] += av.x * bv.y;
            acc[0][2] += av.x * bv.z; acc[0][3] += av.x * bv.w;
            acc[1][0] += av.y * bv.x; acc[1][1] += av.y * bv.y;
            acc[1][2] += av.y * bv.z; acc[1][3] += av.y * bv.w;
            acc[2][0] += av.z * bv.x; acc[2][1] += av.z * bv.y;
            acc[2][2] += av.z * bv.z; acc[2][3] += av.z * bv.w;
            acc[3][0] += av.w * bv.x; acc[3][1] += av.w * bv.y;
            acc[3][2] += av.w * bv.z; acc[3][3] += av.w * bv.w;
        }
        __syncthreads();
    }

    #pragma unroll
    for (int ii = 0; ii < 4; ++ii) {
        const int m = m0 + ty * 4 + ii;
        #pragma unroll
        for (int jq = 0; jq < 4; ++jq) {
            const int v = n0 + tx * 4 + jq;
            if (v < V_) op[(size_t)m * V_ + v] = acc[ii][jq] + bout[v];
        }
    }
}

extern "C" void kernel_launch(void* const* d_in, const int* in_sizes, int n_in,
                              void* d_out, int out_size, void* d_ws, size_t ws_size,
                              hipStream_t stream) {
    const int*   xx    = (const int*)  d_in[0];
    const float* embed = (const float*)d_in[1];
    const float* Whh   = (const float*)d_in[2];
    const float* bhh   = (const float*)d_in[3];
    const float* Wih   = (const float*)d_in[4];
    const float* bih   = (const float*)d_in[5];
    const float* Wh    = (const float*)d_in[6];
    const float* bh    = (const float*)d_in[7];
    const float* Wi    = (const float*)d_in[8];
    const float* bi    = (const float*)d_in[9];
    const float* Wup   = (const float*)d_in[10];
    const float* bup   = (const float*)d_in[11];
    const float* Wout  = (const float*)d_in[12];
    const float* bout  = (const float*)d_in[13];

    float* ws   = (float*)d_ws;
    float* hbuf = ws;                                   // 8192*1024 floats
    float* sHb  = hbuf + (size_t)B_ * T_ * HN_;         // 2*64*256
    float* sNb  = sHb + 2 * B_ * HH_;                   // 2*64*1024

    void* args[] = { (void*)&xx, (void*)&embed, (void*)&Whh, (void*)&bhh,
                     (void*)&Wih, (void*)&bih, (void*)&Wh, (void*)&bh,
                     (void*)&Wi, (void*)&bi, (void*)&Wup, (void*)&bup,
                     (void*)&sHb, (void*)&sNb, (void*)&hbuf };
    hipLaunchCooperativeKernel(reinterpret_cast<void*>(recur_kernel),
                               dim3(256), dim3(256), args,
                               (size_t)(LDS_FLOATS * 4), stream);

    out_gemm<<<dim3(T_ * B_ / 64, (V_ + 63) / 64), 256, 0, stream>>>(
        hbuf, Wout, bout, (float*)d_out);
}